// Round 2
// baseline (956.028 us; speedup 1.0000x reference)
//
#include <hip/hip_runtime.h>

// ---------------- preprocessing ----------------

__global__ void k_count(const int* __restrict__ row, int E, int* __restrict__ cnt) {
    int e = blockIdx.x * blockDim.x + threadIdx.x;
    if (e < E) atomicAdd(&cnt[row[e]], 1);
}

// Allocate contiguous CSR ranges per node via wave-scan + one atomic per wave.
// Order across waves arbitrary — segment-sum is order independent.
__global__ void k_alloc(const int* __restrict__ cnt, int N, int* __restrict__ total,
                        int* __restrict__ rptr, int* __restrict__ cursor,
                        float* __restrict__ dinv) {
    int i = blockIdx.x * blockDim.x + threadIdx.x;
    int lane = threadIdx.x & 63;
    int c = (i < N) ? cnt[i] : 0;
    int v = c;
    #pragma unroll
    for (int off = 1; off < 64; off <<= 1) {
        int n = __shfl_up(v, off);
        if (lane >= off) v += n;
    }
    int wtotal = __shfl(v, 63);
    int base = 0;
    if (lane == 63) base = atomicAdd(total, wtotal);
    base = __shfl(base, 63);
    if (i < N) {
        int start = base + v - c;            // exclusive scan position
        rptr[i] = start;
        cursor[i] = start;
        dinv[i] = rsqrtf((float)(c + 1));    // +1 self-loop; matches ref deg>=1
    }
}

__global__ void k_scatter(const int* __restrict__ row, const int* __restrict__ col, int E,
                          int* __restrict__ cursor, const float* __restrict__ dinv,
                          int* __restrict__ cidx, float* __restrict__ dnc) {
    int e = blockIdx.x * blockDim.x + threadIdx.x;
    if (e < E) {
        int r = row[e], c = col[e];
        int p = atomicAdd(&cursor[r], 1);
        cidx[p] = c;
        dnc[p] = dinv[c];
    }
}

// ---------------- GEMM: T[N,64] = H[N,64] @ W[64,64]  (fp32, VALU) ----------------
// One wave per node: lane = output channel; W staged in LDS (16 KB).
// Ws[k*64+ch]: lanes have ch=0..63 for fixed k -> bank = ch%32, 2 lanes/bank (free).
// H[node*64+k] is wave-uniform -> broadcast, L1-hit.
__global__ void k_gemm(const float* __restrict__ H, const float* __restrict__ W,
                       float* __restrict__ T, int N) {
    __shared__ float Ws[64 * 64];
    for (int i = threadIdx.x; i < 64 * 64; i += blockDim.x) Ws[i] = W[i];
    __syncthreads();
    int gid = blockIdx.x * blockDim.x + threadIdx.x;
    int totalT = N * 64;
    int stride = gridDim.x * blockDim.x;
    for (; gid < totalT; gid += stride) {
        int node = gid >> 6, ch = gid & 63;
        const float* h = H + (size_t)node * 64;
        float acc = 0.f;
        #pragma unroll 16
        for (int k = 0; k < 64; k++) acc = fmaf(h[k], Ws[k * 64 + ch], acc);
        T[gid] = acc;
    }
}

// ---------------- fused propagate + bias + BN + ReLU ----------------
// out[r][ch] = f( dinv[r]*( sum_e dnc[e]*T[cidx[e]][ch] + dinv[r]*T[r][ch] ) + b[ch] )
__global__ void k_agg(const float* __restrict__ T, const int* __restrict__ rptr,
                      const int* __restrict__ cnt, const float* __restrict__ dinv,
                      const int* __restrict__ cidx, const float* __restrict__ dnc,
                      const float* __restrict__ bias, const float* __restrict__ g,
                      const float* __restrict__ be, const float* __restrict__ mm,
                      const float* __restrict__ vv, int do_bn,
                      float* __restrict__ out, int N) {
    int lane = threadIdx.x & 63;
    int wid = (blockIdx.x * blockDim.x + threadIdx.x) >> 6;
    int nw = (gridDim.x * blockDim.x) >> 6;

    float bval = bias[lane];
    float sc = 1.f, sh = 0.f;
    if (do_bn) {
        sc = g[lane] * rsqrtf(vv[lane] + 1e-5f);
        sh = be[lane] - mm[lane] * sc;
    }

    for (int r = wid; r < N; r += nw) {
        int start = rptr[r];
        int e = cnt[r];
        float acc = 0.f;
        for (int i = 0; i < e; i++) {
            int c = cidx[start + i];        // wave-uniform
            c = min(max(c, 0), N - 1);      // defensive: bound any bad index
            float w = dnc[start + i];
            acc = fmaf(w, T[(size_t)c * 64 + lane], acc);
        }
        float dr = dinv[r];
        float val = dr * (acc + dr * T[(size_t)r * 64 + lane]) + bval;
        if (do_bn) val = fmaxf(val * sc + sh, 0.f);
        out[(size_t)r * 64 + lane] = val;
    }
}

// ---------------- launcher ----------------

extern "C" void kernel_launch(void* const* d_in, const int* in_sizes, int n_in,
                              void* d_out, int out_size, void* d_ws, size_t ws_size,
                              hipStream_t stream) {
    const float* x  = (const float*)d_in[0];
    const int*   ei = (const int*)d_in[1];
    const float *W1 = (const float*)d_in[2],  *b1 = (const float*)d_in[3];
    const float *g1 = (const float*)d_in[4],  *be1= (const float*)d_in[5];
    const float *m1 = (const float*)d_in[6],  *v1 = (const float*)d_in[7];
    const float *W2 = (const float*)d_in[8],  *b2 = (const float*)d_in[9];
    const float *g2 = (const float*)d_in[10], *be2= (const float*)d_in[11];
    const float *m2 = (const float*)d_in[12], *v2 = (const float*)d_in[13];
    const float *W3 = (const float*)d_in[14], *b3 = (const float*)d_in[15];

    int N = in_sizes[0] / 64;
    int E = in_sizes[1] / 2;
    const int* row = ei;
    const int* col = ei + E;

    // workspace partition (256B aligned)
    char* p = (char*)d_ws;
    auto take = [&](size_t b) -> char* {
        char* q = p;
        p += (b + 255) & ~(size_t)255;
        return q;
    };
    int*   cnt    = (int*)  take((size_t)(N + 64) * 4);  // cnt[N..] = total counter
    int*   rptr   = (int*)  take((size_t)N * 4);
    int*   cursor = (int*)  take((size_t)N * 4);
    float* dinv   = (float*)take((size_t)N * 4);
    int*   cidx   = (int*)  take((size_t)E * 4);
    float* dnc    = (float*)take((size_t)E * 4);
    float* t      = (float*)take((size_t)N * 64 * 4);
    float* h1     = (float*)take((size_t)N * 64 * 4);
    int* total = cnt + N;

    hipMemsetAsync(cnt, 0, (size_t)(N + 64) * 4, stream);

    const int TB = 256;
    k_count  <<<(E + TB - 1) / TB, TB, 0, stream>>>(row, E, cnt);
    k_alloc  <<<(N + TB - 1) / TB, TB, 0, stream>>>(cnt, N, total, rptr, cursor, dinv);
    k_scatter<<<(E + TB - 1) / TB, TB, 0, stream>>>(row, col, E, cursor, dinv, cidx, dnc);

    float* outp = (float*)d_out;   // [0, N*64): embeddings, [N*64, 2N*64): predictions
    int gemm_blocks = (N * 64 + TB - 1) / TB;
    const int GA = 2048;           // agg blocks -> 8192 waves

    // layer 1
    k_gemm<<<gemm_blocks, TB, 0, stream>>>(x, W1, t, N);
    k_agg <<<GA, TB, 0, stream>>>(t, rptr, cnt, dinv, cidx, dnc, b1, g1, be1, m1, v1, 1, h1, N);
    // layer 2 -> output 0 (global_embeddings)
    k_gemm<<<gemm_blocks, TB, 0, stream>>>(h1, W2, t, N);
    k_agg <<<GA, TB, 0, stream>>>(t, rptr, cnt, dinv, cidx, dnc, b2, g2, be2, m2, v2, 1, outp, N);
    // layer 3 -> output 1 (hc_predictions), reads embeddings straight from d_out
    k_gemm<<<gemm_blocks, TB, 0, stream>>>(outp, W3, t, N);
    k_agg <<<GA, TB, 0, stream>>>(t, rptr, cnt, dinv, cidx, dnc, b3, b3, b3, b3, b3, 0,
                                  outp + (size_t)N * 64, N);
}

// Round 3
// 534.975 us; speedup vs baseline: 1.7871x; 1.7871x over previous
//
#include <hip/hip_runtime.h>

typedef __attribute__((ext_vector_type(8))) short bfrag8;   // 8 bf16 in 4 VGPRs
typedef __attribute__((ext_vector_type(4))) float facc4;    // 4 fp32 acc

static __device__ __forceinline__ float bf2f(ushort u) {
    union { unsigned int i; float f; } x;
    x.i = ((unsigned int)u) << 16;
    return x.f;
}
static __device__ __forceinline__ ushort f2bf(float f) {
    union { float f; unsigned int i; } x;
    x.f = f;
    unsigned int r = x.i + 0x7FFFu + ((x.i >> 16) & 1u);   // RNE
    return (ushort)(r >> 16);
}

// ---------------- preprocessing ----------------

__global__ void k_count(const int* __restrict__ row, int E, int* __restrict__ cnt) {
    int e = blockIdx.x * blockDim.x + threadIdx.x;
    if (e < E) atomicAdd(&cnt[row[e]], 1);
}

// CSR range allocation: wave-scan + one global atomic per wave.
__global__ void k_alloc(const int* __restrict__ cnt, int N, int* __restrict__ total,
                        int* __restrict__ rptr, int* __restrict__ cursor,
                        float* __restrict__ dinv) {
    int i = blockIdx.x * blockDim.x + threadIdx.x;
    int lane = threadIdx.x & 63;
    int c = (i < N) ? cnt[i] : 0;
    int v = c;
    #pragma unroll
    for (int off = 1; off < 64; off <<= 1) {
        int n = __shfl_up(v, off);
        if (lane >= off) v += n;
    }
    int wtotal = __shfl(v, 63);
    int base = 0;
    if (lane == 63) base = atomicAdd(total, wtotal);
    base = __shfl(base, 63);
    if (i < N) {
        int start = base + v - c;
        rptr[i] = start;
        cursor[i] = start;
        dinv[i] = rsqrtf((float)(c + 1));    // +1 self-loop
    }
}

__global__ void k_scatter(const int* __restrict__ row, const int* __restrict__ col, int E,
                          int* __restrict__ cursor, int* __restrict__ cidx) {
    int e = blockIdx.x * blockDim.x + threadIdx.x;
    if (e < E) {
        int r = row[e];
        int p = atomicAdd(&cursor[r], 1);
        cidx[p] = col[e];      // single 4B scattered store (dnc dropped: agg reads dinv[c])
    }
}

// ---------------- fp32 -> bf16 convert (for x) ----------------
__global__ void k_cvt(const float* __restrict__ in, ushort* __restrict__ out, int n4) {
    int i = blockIdx.x * blockDim.x + threadIdx.x;
    if (i < n4) {
        float4 v = ((const float4*)in)[i];
        ushort4 o;
        o.x = f2bf(v.x); o.y = f2bf(v.y); o.z = f2bf(v.z); o.w = f2bf(v.w);
        ((ushort4*)out)[i] = o;
    }
}

// ---------------- MFMA GEMM: T[N,64] = H[N,64] @ W[64,64]  (bf16 in/out, fp32 W src) ----------------
// mfma_f32_16x16x32_bf16: A[m=lane&15][k=quad*8+j]; B[k=quad*8+j][n=lane&15];
// D row=quad*4+reg, col=lane&15.
__global__ void k_gemm(const ushort* __restrict__ H, const float* __restrict__ W,
                       ushort* __restrict__ T, int ntiles, int N) {
    int lane = threadIdx.x & 63;
    int wid = (blockIdx.x * blockDim.x + threadIdx.x) >> 6;
    int nw = (gridDim.x * blockDim.x) >> 6;
    int m = lane & 15, quad = lane >> 4;

    // All of W in B-fragments: [kstep s][chtile c] -> 8 frags, 32 VGPRs. Loaded once.
    bfrag8 bf[2][4];
    #pragma unroll
    for (int s = 0; s < 2; s++)
        #pragma unroll
        for (int c = 0; c < 4; c++) {
            bfrag8 f;
            #pragma unroll
            for (int j = 0; j < 8; j++) {
                int k = 32 * s + quad * 8 + j;
                f[j] = (short)f2bf(W[k * 64 + 16 * c + m]);
            }
            bf[s][c] = f;
        }

    for (int t = wid; t < ntiles; t += nw) {
        int nodeA = t * 16 + m;
        if (nodeA >= N) nodeA = N - 1;
        const ushort* arow = H + (size_t)nodeA * 64;
        bfrag8 a0 = *(const bfrag8*)(arow + quad * 8);        // k 0..31  (16B aligned)
        bfrag8 a1 = *(const bfrag8*)(arow + 32 + quad * 8);   // k 32..63
        facc4 acc[4];
        #pragma unroll
        for (int c = 0; c < 4; c++) { acc[c][0]=0.f; acc[c][1]=0.f; acc[c][2]=0.f; acc[c][3]=0.f; }
        #pragma unroll
        for (int c = 0; c < 4; c++) {
            acc[c] = __builtin_amdgcn_mfma_f32_16x16x32_bf16(a0, bf[0][c], acc[c], 0, 0, 0);
            acc[c] = __builtin_amdgcn_mfma_f32_16x16x32_bf16(a1, bf[1][c], acc[c], 0, 0, 0);
        }
        #pragma unroll
        for (int c = 0; c < 4; c++)
            #pragma unroll
            for (int r = 0; r < 4; r++) {
                int node = t * 16 + quad * 4 + r;
                if (node < N) T[(size_t)node * 64 + c * 16 + m] = f2bf(acc[c][r]);
            }
    }
}

// ---------------- fused propagate + bias + BN + ReLU ----------------
// out[r][ch] = f( dinv[r]*( sum_e dinv[cidx[e]]*T[cidx[e]][ch] + dinv[r]*T[r][ch] ) + b[ch] )
// 8-wide unrolled gather for memory-level parallelism (lat-bound per round-2 rocprof).
__global__ void k_agg(const ushort* __restrict__ T, const int* __restrict__ rptr,
                      const int* __restrict__ cnt, const float* __restrict__ dinv,
                      const int* __restrict__ cidx,
                      const float* __restrict__ bias, const float* __restrict__ g,
                      const float* __restrict__ be, const float* __restrict__ mm,
                      const float* __restrict__ vv, int do_bn,
                      float* __restrict__ outf, ushort* __restrict__ outb, int N) {
    int lane = threadIdx.x & 63;
    int wid = (blockIdx.x * blockDim.x + threadIdx.x) >> 6;
    int nw = (gridDim.x * blockDim.x) >> 6;

    float bval = bias[lane];
    float sc = 1.f, sh = 0.f;
    if (do_bn) {
        sc = g[lane] * rsqrtf(vv[lane] + 1e-5f);
        sh = be[lane] - mm[lane] * sc;
    }

    for (int r = wid; r < N; r += nw) {
        int start = rptr[r];
        int e = cnt[r];
        float acc0 = 0.f, acc1 = 0.f;
        int i = 0;
        for (; i + 8 <= e; i += 8) {
            int c0 = cidx[start + i + 0];
            int c1 = cidx[start + i + 1];
            int c2 = cidx[start + i + 2];
            int c3 = cidx[start + i + 3];
            int c4 = cidx[start + i + 4];
            int c5 = cidx[start + i + 5];
            int c6 = cidx[start + i + 6];
            int c7 = cidx[start + i + 7];
            float w0 = dinv[c0], w1 = dinv[c1], w2 = dinv[c2], w3 = dinv[c3];
            float w4 = dinv[c4], w5 = dinv[c5], w6 = dinv[c6], w7 = dinv[c7];
            float t0 = bf2f(T[(size_t)c0 * 64 + lane]);
            float t1 = bf2f(T[(size_t)c1 * 64 + lane]);
            float t2 = bf2f(T[(size_t)c2 * 64 + lane]);
            float t3 = bf2f(T[(size_t)c3 * 64 + lane]);
            float t4 = bf2f(T[(size_t)c4 * 64 + lane]);
            float t5 = bf2f(T[(size_t)c5 * 64 + lane]);
            float t6 = bf2f(T[(size_t)c6 * 64 + lane]);
            float t7 = bf2f(T[(size_t)c7 * 64 + lane]);
            acc0 = fmaf(w0, t0, acc0); acc1 = fmaf(w1, t1, acc1);
            acc0 = fmaf(w2, t2, acc0); acc1 = fmaf(w3, t3, acc1);
            acc0 = fmaf(w4, t4, acc0); acc1 = fmaf(w5, t5, acc1);
            acc0 = fmaf(w6, t6, acc0); acc1 = fmaf(w7, t7, acc1);
        }
        for (; i < e; i++) {
            int c = cidx[start + i];
            acc0 = fmaf(dinv[c], bf2f(T[(size_t)c * 64 + lane]), acc0);
        }
        float dr = dinv[r];
        float val = dr * (acc0 + acc1 + dr * bf2f(T[(size_t)r * 64 + lane])) + bval;
        if (do_bn) val = fmaxf(val * sc + sh, 0.f);
        if (outf) outf[(size_t)r * 64 + lane] = val;
        if (outb) outb[(size_t)r * 64 + lane] = f2bf(val);
    }
}

// ---------------- launcher ----------------

extern "C" void kernel_launch(void* const* d_in, const int* in_sizes, int n_in,
                              void* d_out, int out_size, void* d_ws, size_t ws_size,
                              hipStream_t stream) {
    const float* x  = (const float*)d_in[0];
    const int*   ei = (const int*)d_in[1];
    const float *W1 = (const float*)d_in[2],  *b1 = (const float*)d_in[3];
    const float *g1 = (const float*)d_in[4],  *be1= (const float*)d_in[5];
    const float *m1 = (const float*)d_in[6],  *v1 = (const float*)d_in[7];
    const float *W2 = (const float*)d_in[8],  *b2 = (const float*)d_in[9];
    const float *g2 = (const float*)d_in[10], *be2= (const float*)d_in[11];
    const float *m2 = (const float*)d_in[12], *v2 = (const float*)d_in[13];
    const float *W3 = (const float*)d_in[14], *b3 = (const float*)d_in[15];

    int N = in_sizes[0] / 64;
    int E = in_sizes[1] / 2;
    const int* row = ei;
    const int* col = ei + E;

    char* p = (char*)d_ws;
    auto take = [&](size_t b) -> char* {
        char* q = p;
        p += (b + 255) & ~(size_t)255;
        return q;
    };
    int*    cnt    = (int*)   take((size_t)(N + 64) * 4);   // cnt[N..] = total counter
    int*    rptr   = (int*)   take((size_t)N * 4);
    int*    cursor = (int*)   take((size_t)N * 4);
    float*  dinv   = (float*) take((size_t)N * 4);
    int*    cidx   = (int*)   take((size_t)E * 4);
    ushort* xb     = (ushort*)take((size_t)N * 64 * 2);
    ushort* t      = (ushort*)take((size_t)N * 64 * 2);     // pre-propagate features
    ushort* h      = (ushort*)take((size_t)N * 64 * 2);     // post-activation features
    int* total = cnt + N;

    hipMemsetAsync(cnt, 0, (size_t)(N + 64) * 4, stream);

    const int TB = 256;
    k_count  <<<(E + TB - 1) / TB, TB, 0, stream>>>(row, E, cnt);
    k_alloc  <<<(N + TB - 1) / TB, TB, 0, stream>>>(cnt, N, total, rptr, cursor, dinv);
    k_scatter<<<(E + TB - 1) / TB, TB, 0, stream>>>(row, col, E, cursor, cidx);

    int n4 = N * 64 / 4;
    k_cvt<<<(n4 + TB - 1) / TB, TB, 0, stream>>>(x, xb, n4);

    float* outp = (float*)d_out;   // [0, N*64): embeddings fp32; [N*64, 2N*64): preds
    int ntiles = (N + 15) >> 4;
    const int GG = 512;    // gemm blocks (persistent waves)
    const int GA = 2048;   // agg blocks -> 8192 waves (8 blocks/CU)

    // layer 1
    k_gemm<<<GG, TB, 0, stream>>>(xb, W1, t, ntiles, N);
    k_agg <<<GA, TB, 0, stream>>>(t, rptr, cnt, dinv, cidx, b1, g1, be1, m1, v1, 1,
                                  (float*)nullptr, h, N);
    // layer 2 -> embeddings (fp32 to d_out) + bf16 h for layer 3
    k_gemm<<<GG, TB, 0, stream>>>(h, W2, t, ntiles, N);
    k_agg <<<GA, TB, 0, stream>>>(t, rptr, cnt, dinv, cidx, b2, g2, be2, m2, v2, 1,
                                  outp, h, N);
    // layer 3 -> predictions
    k_gemm<<<GG, TB, 0, stream>>>(h, W3, t, ntiles, N);
    k_agg <<<GA, TB, 0, stream>>>(t, rptr, cnt, dinv, cidx, b3, b3, b3, b3, b3, 0,
                                  outp + (size_t)N * 64, (ushort*)nullptr, N);
}